// Round 12
// baseline (6093.117 us; speedup 1.0000x reference)
//
#include <hip/hip_runtime.h>
#include <math.h>

#define BATCH 1024
#define SEQ   256
#define UNITS 256
#define NC    128

typedef __attribute__((ext_vector_type(8))) short  short8;   // 8 bf16 = 4 regs
typedef __attribute__((ext_vector_type(4))) float  float4v;  // MFMA C/D
typedef unsigned long long u64;
typedef unsigned int       u32;
typedef unsigned short     u16;

// Gate math (validated r1-r11: absmax <= 6.1e-5 vs 1.72e-4 threshold)
__device__ __forceinline__ float sigf(float x)  { return 1.f / (1.f + __expf(-x)); }
__device__ __forceinline__ float tanhf_(float x){ return 1.f - 2.f / (1.f + __expf(2.f * x)); }

__device__ __forceinline__ u16 bf16rne(float f) {
    unsigned u = __float_as_uint(f);
    return (u16)((u + 0x7fffu + ((u >> 16) & 1u)) >> 16);
}
__device__ __forceinline__ float bf16tof(u16 s) {
    return __uint_as_float(((unsigned)s) << 16);
}

// ---------------------------------------------------------------------------
// prep: R0t/R1t[col][k] bf16 split (col = g*256+u, r4-verified layout);
//       Wkb[ch][u*4+g] = Wk + bias (gate-packed).
__global__ __launch_bounds__(256) void prep(
    const float* __restrict__ R, const float* __restrict__ Wk,
    const float* __restrict__ bias,
    u16* __restrict__ R0t, u16* __restrict__ R1t, float* __restrict__ Wkb)
{
    int i = blockIdx.x * 256 + threadIdx.x;    // 0..262143
    int col = i >> 8, k = i & 255;
    float v = R[k * 1024 + col];
    u16 r0 = bf16rne(v);
    R0t[i] = r0;
    R1t[i] = bf16rne(v - bf16tof(r0));
    if (i < NC * 1024) {
        int r = i & 1023;
        int u = r >> 2, g = r & 3;
        int src = (g << 8) + u;
        Wkb[i] = Wk[(i >> 10) * 1024 + src] + bias[src];
    }
}

// ---------------------------------------------------------------------------
// Persistent LSTM, ZERO cross-block sync (r12). r9-r11 measured a ~2-3.5us
// per-step tax for any h exchange through the MALL (store-ack + flag
// visibility + load); r12 removes the exchange instead of hiding it.
// Grid 64 x 1024 thr: block = 16 batches x ALL 256 units (16 waves of 16
// units; 4 waves/SIMD x (180 VGPR + 256 AGPR) = 1776 <= 2048 regs/SIMD).
// The whole recurrence for one 16-batch group runs on ONE CU: h is
// bf16-split in double-buffered LDS planes; epilogue ds_write_b16, next
// step ds_read_b128; one __syncthreads per step; no atomics, no deadlock.
// B-frags in 256 AGPRs (r8-validated inline-asm MFMA), 3-product split.
// MFMA-throughput-bound: 1536 MFMA/CU/step ~ 2.7us.
__global__ __launch_bounds__(1024, 1) void lstm_persist(
    const u16* __restrict__ R0t, const u16* __restrict__ R1t,
    const float* __restrict__ Wkb, const int* __restrict__ inp,
    u32* __restrict__ Hfin)
{
    __shared__ u32 L[2][2][16 * 132];   // [buf][plane][batch*132 + u32col]

    const int tid  = threadIdx.x;
    const int lane = tid & 63;
    const int wv   = tid >> 6;            // 0..15
    const int nl   = lane & 15;
    const int quad = lane >> 4;
    const int u    = (wv << 4) + nl;      // lane's unit (0..255)
    const int bm   = blockIdx.x << 4;     // block's 16-batch base

    // B-frags (r4-verified layout) -> exactly 256 AGPRs, pinned (r8).
    short8 B0[4][8], B1[4][8];
#pragma unroll
    for (int g = 0; g < 4; g++)
#pragma unroll
        for (int kt = 0; kt < 8; kt++) {
            const int idx = ((g << 8) + u) * 256 + (kt << 5) + (quad << 3);
            B0[g][kt] = *(const short8*)&R0t[idx];
            B1[g][kt] = *(const short8*)&R1t[idx];
        }
#pragma unroll
    for (int g = 0; g < 4; g++)
#pragma unroll
        for (int kt = 0; kt < 8; kt++) {
            asm volatile("" : "+a"(B0[g][kt]));
            asm volatile("" : "+a"(B1[g][kt]));
        }

    // h_0 = 0: zero buffer 0 (both planes).
    for (int i = tid; i < 2 * 16 * 132; i += 1024) {
        L[0][0][i] = 0u;   // covers plane0 then plane1 via flat index
    }
    // flat hack above covers L[0][0..1] since they are contiguous
    __syncthreads();

    float c[4] = {0.f, 0.f, 0.f, 0.f};

    for (int t = 0; t < SEQ; t++) {
        const int cur = t & 1;
        const int nxt = cur ^ 1;

        // inp + Wkb gathers (global, L1/L2-hot), issued at step top,
        // consumed in the epilogue -> latency hidden by MFMA.
        int ch[4];
#pragma unroll
        for (int r = 0; r < 4; r++)
            ch[r] = inp[(bm + (quad << 2) + r) * SEQ + t];
        float4v wk[4];
#pragma unroll
        for (int r = 0; r < 4; r++)
            wk[r] = *(const float4v*)&Wkb[(ch[r] << 10) + (u << 2)];

        // MFMA: A-frags from LDS planes (broadcast across the 16 waves),
        // B from AGPRs, 3-product bf16 split (r8-validated numerics).
        float4v acc[4];
#pragma unroll
        for (int kt = 0; kt < 8; kt++) {
            short8 a0 = *(const short8*)&L[cur][0][nl * 132 + (kt << 4) + (quad << 2)];
            short8 a1 = *(const short8*)&L[cur][1][nl * 132 + (kt << 4) + (quad << 2)];
            if (kt == 0) {
#pragma unroll
                for (int g = 0; g < 4; g++) {
                    asm volatile("v_mfma_f32_16x16x32_bf16 %0, %1, %2, 0"
                                 : "=v"(acc[g]) : "v"(a0), "a"(B0[g][0]));
                    asm volatile("v_mfma_f32_16x16x32_bf16 %0, %1, %2, %0"
                                 : "+v"(acc[g]) : "v"(a1), "a"(B0[g][0]));
                    asm volatile("v_mfma_f32_16x16x32_bf16 %0, %1, %2, %0"
                                 : "+v"(acc[g]) : "v"(a0), "a"(B1[g][0]));
                }
            } else {
#pragma unroll
                for (int g = 0; g < 4; g++) {
                    asm volatile("v_mfma_f32_16x16x32_bf16 %0, %1, %2, %0"
                                 : "+v"(acc[g]) : "v"(a0), "a"(B0[g][kt]));
                    asm volatile("v_mfma_f32_16x16x32_bf16 %0, %1, %2, %0"
                                 : "+v"(acc[g]) : "v"(a1), "a"(B0[g][kt]));
                    asm volatile("v_mfma_f32_16x16x32_bf16 %0, %1, %2, %0"
                                 : "+v"(acc[g]) : "v"(a0), "a"(B1[g][kt]));
                }
            }
        }
        // Sound hazard barrier (r10-validated): acc is an operand.
        asm volatile("s_nop 7\n\ts_nop 7\n\ts_nop 7"
                     : "+v"(acc[0]), "+v"(acc[1]), "+v"(acc[2]), "+v"(acc[3]));

        // Epilogue: lane owns (batch = quad*4+r, unit = u). Write bf16-split
        // h straight into the NEXT LDS buffer (b16 stores; 2-way aliasing of
        // even/odd u in one u32 is conflict-free).
        u16* const p0 = (u16*)&L[nxt][0][0];
        u16* const p1 = (u16*)&L[nxt][1][0];
#pragma unroll
        for (int r = 0; r < 4; r++) {
            const int b = (quad << 2) + r;
            float zi = acc[0][r] + wk[r].x;
            float zf = acc[1][r] + wk[r].y;
            float zg = acc[2][r] + wk[r].z;
            float zo = acc[3][r] + wk[r].w;
            float ig = sigf(zi), fg = sigf(zf), gg = tanhf_(zg), og = sigf(zo);
            float cn = fg * c[r] + ig * gg;
            c[r] = cn;
            float hv = og * tanhf_(cn);
            u16 h0 = bf16rne(hv);
            u16 h1 = bf16rne(hv - bf16tof(h0));
            p0[b * 264 + u] = h0;     // (b*132 + u/2)*2 + (u&1) == b*264 + u
            p1[b * 264 + u] = h1;
            if (t == SEQ - 1) {
                Hfin[(bm + b) * 256 + u] = (u32)h0 | ((u32)h1 << 16);
            }
        }

        // One intra-CU barrier per step: separates this step's writes to
        // L[nxt] from next step's reads of it (reads of L[cur] already done
        // above, and next step writes L[cur] only after its own barrier).
        __syncthreads();
    }
}

// ---------------------------------------------------------------------------
// logits = h_last @ dense_w + dense_b ; softmax. h unpacked = lo + hi bf16.
__global__ __launch_bounds__(128) void dense_softmax(
    const u32* __restrict__ H01, const float* __restrict__ W,
    const float* __restrict__ b, float* __restrict__ out)
{
    __shared__ float hsr[UNITS];
    __shared__ float red[NC];
    const int bq = blockIdx.x;
    const int n  = threadIdx.x;

    u32 v0 = H01[bq * 256 + n];
    u32 v1 = H01[bq * 256 + n + 128];
    hsr[n]       = bf16tof((u16)(v0 & 0xffffu)) + bf16tof((u16)(v0 >> 16));
    hsr[n + 128] = bf16tof((u16)(v1 & 0xffffu)) + bf16tof((u16)(v1 >> 16));
    __syncthreads();

    float acc = b[n];
#pragma unroll 8
    for (int k = 0; k < UNITS; k++) acc += hsr[k] * W[k * NC + n];

    red[n] = acc;
    __syncthreads();
    for (int s = 64; s > 0; s >>= 1) {
        if (n < s) red[n] = fmaxf(red[n], red[n + s]);
        __syncthreads();
    }
    float m = red[0];
    __syncthreads();

    float e = __expf(acc - m);
    red[n] = e;
    __syncthreads();
    for (int s = 64; s > 0; s >>= 1) {
        if (n < s) red[n] = red[n] + red[n + s];
        __syncthreads();
    }
    out[bq * NC + n] = e / red[0];
}

// ---------------------------------------------------------------------------
extern "C" void kernel_launch(void* const* d_in, const int* in_sizes, int n_in,
                              void* d_out, int out_size, void* d_ws, size_t ws_size,
                              hipStream_t stream)
{
    const int*   inp  = (const int*)d_in[0];    // [1024][256]
    const float* Wk   = (const float*)d_in[1];  // [128][1024]
    const float* R    = (const float*)d_in[2];  // [256][1024]
    const float* bias = (const float*)d_in[3];  // [1024]
    const float* Wd   = (const float*)d_in[4];  // [256][128]
    const float* bd   = (const float*)d_in[5];  // [128]
    float* out = (float*)d_out;

    // ws: R0t|R1t (512KB ea) | Wkb (512KB) | Hfin (1MB)
    u16*   R0t  = (u16*)d_ws;
    u16*   R1t  = R0t + 262144;
    float* Wkb  = (float*)(R1t + 262144);
    u32*   Hfin = (u32*)(Wkb + 131072);

    prep<<<dim3(1024), dim3(256), 0, stream>>>(R, Wk, bias, R0t, R1t, Wkb);

    lstm_persist<<<dim3(64), dim3(1024), 0, stream>>>(R0t, R1t, Wkb, inp, Hfin);

    dense_softmax<<<dim3(BATCH), dim3(128), 0, stream>>>(Hfin, Wd, bd, out);
}